// Round 8
// baseline (224.286 us; speedup 1.0000x reference)
//
#include <hip/hip_runtime.h>
#include <hip/hip_bf16.h>
#include <stdint.h>

typedef unsigned short u16;
typedef __attribute__((ext_vector_type(8))) short bf16x8;
typedef __attribute__((ext_vector_type(4))) float f32x4;

#define B_    8
#define L_    273
#define DIM_  1536
#define NH_   12
#define DH_   128
#define ZS_   256
#define FH_   32
#define MROWS (B_ * L_)   /* 2184 */
#define MPAD  2304        /* 18 * 128 */
#define NQKV  4608
#define WN_   (DIM_ * DIM_)      /* 2,359,296 */
#define WN8_  (WN_ / 8)          /* 294,912   */
#define X8_   (MROWS * DIM_ / 8) /* 419,328   */
#define XT8_  (MPAD * DIM_ / 8)  /* 442,368   */

/* prep_kernel region boundaries (threads); sctab has 33 frames (32 cached + cf) */
#define N0_ 442368
#define N1_ 737280
#define N2_ 1032192
#define N3_ 1327104
#define N4_ 1622016
#define N5_ 1626624
#define N6_ 2167296
#define PREP_BLKS 8466

/* attention geometry */
#define ATTN_ITEMS (B_ * ZS_ * 6)     /* 12288 */
#define ATTN_BLKS  (ATTN_ITEMS / 2)   /* 6144  */
#define VCOND_TOT  (B_ * (L_ - ZS_) * DIM_ / 8)  /* 26112 */
#define VCOND_BLKS ((VCOND_TOT + 255) / 256)     /* 102   */

#define KSPLIT 768

/* workspace offsets (bytes), all 16B-aligned */
#define OFF_XB    0ULL                      /* 2304*1536*2  = 7,077,888  */
#define OFF_WB    7077888ULL                /* 4608*1536*2  = 14,155,776 */
#define OFF_WOB   21233664ULL               /* 1536*1536*2  = 4,718,592  */
#define OFF_BQKV  25952256ULL               /* 4608*4       = 18,432     */
#define OFF_CQKV  25970688ULL               /* 2304*4608*2  = 21,233,664 (bf16) */
#define OFF_ATTN  47204352ULL               /* 2304*1536*2  = 7,077,888  */
#define OFF_SC    54282240ULL               /* 33*256*128*4 = 4,325,376  */
#define OFF_RMS   58607616ULL               /* 2*2048*4     = 16,384     */
/* split-K bf16 partials overlay dead regions:
 * p0 = [0, 7,077,888)           over xb        (dead after QKV GEMM)
 * p1 = [25,970,688, 33,048,576) over Cq        (dead after attention) */
#define OFF_P0    0ULL
#define OFF_P1    25970688ULL

__device__ __forceinline__ u16 f2bf(float f) {
  __hip_bfloat16 h = __float2bfloat16(f);
  return *reinterpret_cast<u16*>(&h);
}
__device__ __forceinline__ float bf2f(u16 v) {
  uint32_t u = ((uint32_t)v) << 16;
  return __uint_as_float(u);
}

__device__ __forceinline__ void gload_lds16(const u16* g, u16* l) {
  __builtin_amdgcn_global_load_lds(
      (const __attribute__((address_space(1))) void*)g,
      (__attribute__((address_space(3))) void*)l,
      16, 0, 0);
}

__device__ __forceinline__ void cast8(const float* __restrict__ s, u16* __restrict__ d,
                                      int i, int nvalid) {
  uint4 o;
  if (i < nvalid) {
    const float4 a = ((const float4*)s)[i * 2];
    const float4 b = ((const float4*)s)[i * 2 + 1];
    o.x = (uint32_t)f2bf(a.x) | ((uint32_t)f2bf(a.y) << 16);
    o.y = (uint32_t)f2bf(a.z) | ((uint32_t)f2bf(a.w) << 16);
    o.z = (uint32_t)f2bf(b.x) | ((uint32_t)f2bf(b.y) << 16);
    o.w = (uint32_t)f2bf(b.z) | ((uint32_t)f2bf(b.w) << 16);
  } else {
    o = make_uint4(0, 0, 0, 0);
  }
  ((uint4*)d)[i] = o;
}

/* ---- all input prep in ONE launch: casts, bias pack, rope sincos table.
 *      sctab frame 32 = current frame cf (for q-rope). ---- */
__global__ __launch_bounds__(256)
void prep_kernel(const float* __restrict__ x, const float* __restrict__ w_q,
                 const float* __restrict__ w_k, const float* __restrict__ w_v,
                 const float* __restrict__ w_o, const float* __restrict__ bq,
                 const float* __restrict__ bk, const float* __restrict__ bv,
                 const float* __restrict__ rope_tb, const int* __restrict__ rope_ix,
                 const int* __restrict__ cf_ptr,
                 u16* __restrict__ xb, u16* __restrict__ wb, u16* __restrict__ wob,
                 float* __restrict__ bqkv, float* __restrict__ sctab) {
  const int t = blockIdx.x * 256 + threadIdx.x;
  if (t < N0_)      cast8(x,   xb,           t,       X8_);
  else if (t < N1_) cast8(w_q, wb,           t - N0_, WN8_);
  else if (t < N2_) cast8(w_k, wb + WN_,     t - N1_, WN8_);
  else if (t < N3_) cast8(w_v, wb + 2 * WN_, t - N2_, WN8_);
  else if (t < N4_) cast8(w_o, wob,          t - N3_, WN8_);
  else if (t < N5_) {
    int i = t - N4_;
    float v;
    if (i < DIM_)          v = bq[i];
    else if (i < 2 * DIM_) v = bk[i - DIM_];
    else                   v = bv[i - 2 * DIM_];
    bqkv[i] = v;
  } else if (t < N6_) {
    int u = t - N5_;
    int j = u & 63;
    int idx = u >> 6;              /* f*ZS + z, f in [0,33) */
    int f = idx >> 8, z = idx & 255;
    int fi = (f == 32) ? *cf_ptr : rope_ix[f];
    float fr = rope_tb[((size_t)fi * L_ + z) * 64 + j];
    float sn, cn;
    __sincosf(fr, &sn, &cn);
    *(float2*)&sctab[((size_t)idx << 7) + 2 * j] = make_float2(sn, cn);
  }
}

/* ---- bf16 GEMM, C[m,n] = sum_k A[m,k]*B[n,k] (+bias)  (NT layout) ----
 * 128x128 tile, BK=32, 4 waves (2x2), double-buffered LDS, stage-early
 * (T3-minimum: one barrier per K-step). XCD-chunked block swizzle
 * (requires gridDim.x*gridDim.y % 8 == 0).
 * mode 1: bf16 out + bias; 2: bf16 partial (split-K via blockIdx.z, no bias). */
__global__ __launch_bounds__(256)
void gemm_bt_kernel(const u16* __restrict__ A, const u16* __restrict__ Bm,
                    const float* __restrict__ bias, void* __restrict__ Cv,
                    void* __restrict__ Cv2,
                    int K, int ldc, int Mvalid, int mode, int ksplit) {
  /* XCD swizzle: chunk tile-space so each XCD gets contiguous tiles */
  const int nwg = gridDim.x * gridDim.y;
  const int lin = blockIdx.y * gridDim.x + blockIdx.x;
  const int nl = (lin & 7) * (nwg >> 3) + (lin >> 3);
  const int tn = nl % gridDim.x, tm = nl / gridDim.x;

  const int tid = threadIdx.x;
  const int lane = tid & 63;
  const int wid = tid >> 6;
  const int wm = wid >> 1, wn = wid & 1;

  __shared__ __align__(16) u16 As[2][128 * 32];
  __shared__ __align__(16) u16 Bs[2][128 * 32];

  f32x4 acc[4][4] = {};

  const int srow = tid >> 2;
  const int scol = (tid & 3) * 8;
  const u16* Abase = A + (size_t)(tm * 128 + srow) * K + scol;
  const u16* Bbase = Bm + (size_t)(tn * 128 + srow) * K + scol;
  const size_t rstep = (size_t)64 * K;
  const int lofs = srow * 32 + scol;

  const int ko = (lane >> 4) * 8;
  const int rA = wm * 64 + (lane & 15);
  const int rB = wn * 64 + (lane & 15);

  const int k0 = blockIdx.z * ksplit;
  const int k1 = k0 + ksplit;

  gload_lds16(Abase + k0,         &As[0][lofs]);
  gload_lds16(Abase + k0 + rstep, &As[0][64 * 32 + lofs]);
  gload_lds16(Bbase + k0,         &Bs[0][lofs]);
  gload_lds16(Bbase + k0 + rstep, &Bs[0][64 * 32 + lofs]);
  __syncthreads();

  int cur = 0;
  for (int kt = k0; kt < k1; kt += 32) {
    const int nx = cur ^ 1;
    if (kt + 32 < k1) {           /* issue next-tile loads BEFORE compute */
      gload_lds16(Abase + kt + 32,         &As[nx][lofs]);
      gload_lds16(Abase + kt + 32 + rstep, &As[nx][64 * 32 + lofs]);
      gload_lds16(Bbase + kt + 32,         &Bs[nx][lofs]);
      gload_lds16(Bbase + kt + 32 + rstep, &Bs[nx][64 * 32 + lofs]);
    }
    bf16x8 af[4], bfr[4];
#pragma unroll
    for (int f = 0; f < 4; ++f) {
      af[f]  = *(const bf16x8*)&As[cur][(rA + f * 16) * 32 + ko];
      bfr[f] = *(const bf16x8*)&Bs[cur][(rB + f * 16) * 32 + ko];
    }
#pragma unroll
    for (int fm = 0; fm < 4; ++fm)
#pragma unroll
      for (int fn = 0; fn < 4; ++fn)
        acc[fm][fn] = __builtin_amdgcn_mfma_f32_16x16x32_bf16(af[fm], bfr[fn], acc[fm][fn], 0, 0, 0);
    __syncthreads();
    cur = nx;
  }

  const int m0 = tm * 128 + wm * 64 + (lane >> 4) * 4;
  const int n0 = tn * 128 + wn * 64 + (lane & 15);
  u16* Cp = (u16*)((mode == 2 && blockIdx.z) ? Cv2 : Cv);
#pragma unroll
  for (int fm = 0; fm < 4; ++fm) {
#pragma unroll
    for (int fn = 0; fn < 4; ++fn) {
      const int n = n0 + fn * 16;
      const float bv = (mode == 2) ? 0.f : bias[n];
#pragma unroll
      for (int r = 0; r < 4; ++r) {
        const int m = m0 + fm * 16 + r;
        if (m < Mvalid) {
          const float val = acc[fm][fn][r] + bv;
          Cp[(size_t)m * ldc + n] = f2bf(val);
        }
      }
    }
  }
}

/* ---- per-row rsqrt(mean(sq)) for q,k sections; z<ZS rows only.
 *      rms[sec*2048 + b*ZS + z]. One wave per (row, sec). ---- */
__global__ __launch_bounds__(256)
void rms_kernel(const u16* __restrict__ Cq, float* __restrict__ rms) {
  const int w = blockIdx.x * 4 + (threadIdx.x >> 6);   /* 0..4095 */
  const int lane = threadIdx.x & 63;
  const int sec = w & 1;
  const int rid = w >> 1;                              /* 0..2047 */
  const int b = rid >> 8, z = rid & 255;
  const u16* p = Cq + (size_t)(b * L_ + z) * NQKV + sec * DIM_;
  float ss = 0.f;
#pragma unroll
  for (int j = 0; j < 3; ++j) {
    bf16x8 v = *(const bf16x8*)&p[lane * 8 + j * 512];
#pragma unroll
    for (int e = 0; e < 8; ++e) {
      float f = bf2f((u16)v[e]);
      ss += f * f;
    }
  }
#pragma unroll
  for (int o = 32; o; o >>= 1) ss += __shfl_xor(ss, o);
  if (lane == 0)
    rms[sec * 2048 + rid] = rsqrtf(ss * (1.f / DIM_) + 1e-6f);
}

/* ---- attention: 2 waves per (b,z,head-pair) split over g; LDS merge.
 *      RMSNorm + gains + rope applied inline on raw q / slot-k.
 *      Depth-2 software pipeline: k/v/sc prefetch + dual interleaved
 *      shuffle-reduce; softmax updates applied sequentially in g order
 *      (bit-identical accumulation). vcond blocks appended at grid end. ---- */
__global__ __launch_bounds__(256)
void attention_kernel(const u16* __restrict__ Cq, const float* __restrict__ cache_k,
                      const float* __restrict__ cache_v, const float* __restrict__ sctab,
                      const float* __restrict__ rms, const float* __restrict__ g_q,
                      const float* __restrict__ g_k,
                      const int* __restrict__ cf_ptr, u16* __restrict__ attn_in) {
  if (blockIdx.x >= ATTN_BLKS) {
    int i = (blockIdx.x - ATTN_BLKS) * 256 + threadIdx.x;
    if (i < VCOND_TOT) {
      int e = i * 8;
      int col = e % DIM_;
      int r = e / DIM_;
      int b = r / (L_ - ZS_);
      int lz = r % (L_ - ZS_);
      size_t mrow = (size_t)b * L_ + ZS_ + lz;
      *(uint4*)&attn_in[mrow * DIM_ + col] = *(const uint4*)&Cq[mrow * NQKV + 2 * DIM_ + col];
    }
    return;
  }

  __shared__ float sm[2][64][6];
  const int p = threadIdx.x >> 7;          /* item within block */
  const int wi = (threadIdx.x >> 6) & 1;   /* wave within item  */
  const int lane = threadIdx.x & 63;
  const int item = blockIdx.x * 2 + p;
  const int hp = item % 6;
  const int z = (item / 6) % ZS_;
  const int b = item / (6 * ZS_);
  const int h = lane >> 5, il = lane & 31;
  const int n = hp * 2 + h;
  const int d0 = il * 4;
  const int cf = *cf_ptr;
  const int slot = cf % FH_;
  const int valid = min(cf + 1, FH_);
  const int g0 = (valid + 1) >> 1;
  const int gs = wi ? g0 : 0;
  const int ge = wi ? valid : g0;

  const size_t crow = (size_t)(b * L_ + z) * NQKV + n * DH_ + d0;
  const float rq = rms[b * ZS_ + z];
  float q0, q1, q2, q3;
  {
    ushort4 qv = *(const ushort4*)&Cq[crow];
    const float4 gq = *(const float4*)&g_q[n * DH_ + d0];
    const float u0 = bf2f(qv.x) * rq * gq.x;
    const float u1 = bf2f(qv.y) * rq * gq.y;
    const float u2 = bf2f(qv.z) * rq * gq.z;
    const float u3 = bf2f(qv.w) * rq * gq.w;
    const float4 scq = *(const float4*)&sctab[((size_t)(32 * ZS_ + z) << 7) + d0];
    q0 = u0 * scq.y - u1 * scq.x;
    q1 = u0 * scq.x + u1 * scq.y;
    q2 = u2 * scq.w - u3 * scq.z;
    q3 = u2 * scq.z + u3 * scq.w;
  }
  const float rk = rms[2048 + b * ZS_ + z];
  const float4 gk = *(const float4*)&g_k[n * DH_ + d0];

  auto loadkv = [&](int g, float4& ko, float4& vo) {
    if (g == slot) {
      ushort4 kv = *(const ushort4*)&Cq[crow + DIM_];
      ushort4 vv = *(const ushort4*)&Cq[crow + 2 * DIM_];
      ko.x = bf2f(kv.x) * rk * gk.x;
      ko.y = bf2f(kv.y) * rk * gk.y;
      ko.z = bf2f(kv.z) * rk * gk.z;
      ko.w = bf2f(kv.w) * rk * gk.w;
      vo.x = bf2f(vv.x); vo.y = bf2f(vv.y); vo.z = bf2f(vv.z); vo.w = bf2f(vv.w);
    } else {
      const size_t coff = ((((size_t)b * FH_ + g) * L_ + z) * NH_ + n) * DH_ + d0;
      ko = *(const float4*)&cache_k[coff];
      vo = *(const float4*)&cache_v[coff];
    }
  };
  auto loadsc = [&](int g) -> float4 {
    return *(const float4*)&sctab[((size_t)(g * ZS_ + z) << 7) + d0];
  };
  auto dotrope = [&](const float4& kk, const float4& sc) -> float {
    const float kr0 = kk.x * sc.y - kk.y * sc.x;
    const float kr1 = kk.x * sc.x + kk.y * sc.y;
    const float kr2 = kk.z * sc.w - kk.w * sc.z;
    const float kr3 = kk.z * sc.z + kk.w * sc.w;
    return q0 * kr0 + q1 * kr1 + q2 * kr2 + q3 * kr3;
  };

  float mx = -1e30f, lsum = 0.f;
  float a0 = 0.f, a1 = 0.f, a2 = 0.f, a3 = 0.f;
  auto update = [&](float part, const float4& vv) {
    const float score = part * 0.088388347648318447f; /* 1/sqrt(128) */
    const float nm = fmaxf(mx, score);
    const float scl = __expf(mx - nm);
    const float pw = __expf(score - nm);
    lsum = lsum * scl + pw;
    a0 = a0 * scl + pw * vv.x;
    a1 = a1 * scl + pw * vv.y;
    a2 = a2 * scl + pw * vv.z;
    a3 = a3 * scl + pw * vv.w;
    mx = nm;
  };

  const int cnt = ge - gs;
  if (cnt > 0) {
    float4 ka, va, sa, kb, vb, sb;
    loadkv(gs, ka, va);
    sa = loadsc(gs);
    if (cnt > 1) { loadkv(gs + 1, kb, vb); sb = loadsc(gs + 1); }
    int g = gs;
    while (g + 1 < ge) {
      float4 kn0 = ka, vn0 = va, sn0 = sa, kn1 = kb, vn1 = vb, sn1 = sb;
      if (g + 2 < ge) { loadkv(g + 2, kn0, vn0); sn0 = loadsc(g + 2); }
      if (g + 3 < ge) { loadkv(g + 3, kn1, vn1); sn1 = loadsc(g + 3); }
      float pa = dotrope(ka, sa);
      float pb = dotrope(kb, sb);
#pragma unroll
      for (int o = 16; o; o >>= 1) {   /* interleaved independent reduces */
        pa += __shfl_xor(pa, o);
        pb += __shfl_xor(pb, o);
      }
      update(pa, va);                  /* sequential, g order preserved */
      update(pb, vb);
      ka = kn0; va = vn0; sa = sn0;
      kb = kn1; vb = vn1; sb = sn1;
      g += 2;
    }
    if (g < ge) {
      float pa = dotrope(ka, sa);
#pragma unroll
      for (int o = 16; o; o >>= 1) pa += __shfl_xor(pa, o);
      update(pa, va);
    }
  }

  if (wi == 1) {
    sm[p][lane][0] = mx;  sm[p][lane][1] = lsum;
    sm[p][lane][2] = a0;  sm[p][lane][3] = a1;
    sm[p][lane][4] = a2;  sm[p][lane][5] = a3;
  }
  __syncthreads();
  if (wi == 0) {
    const float mB = sm[p][lane][0], lB = sm[p][lane][1];
    const float M = fmaxf(mx, mB);
    const float wA = __expf(mx - M), wB = __expf(mB - M);
    const float L = lsum * wA + lB * wB;
    const float inv = 1.f / L;
    const float o0 = (a0 * wA + sm[p][lane][2] * wB) * inv;
    const float o1 = (a1 * wA + sm[p][lane][3] * wB) * inv;
    const float o2 = (a2 * wA + sm[p][lane][4] * wB) * inv;
    const float o3 = (a3 * wA + sm[p][lane][5] * wB) * inv;
    uint2 o;
    o.x = (uint32_t)f2bf(o0) | ((uint32_t)f2bf(o1) << 16);
    o.y = (uint32_t)f2bf(o2) | ((uint32_t)f2bf(o3) << 16);
    *(uint2*)&attn_in[(size_t)(b * L_ + z) * DIM_ + n * DH_ + d0] = o;
  }
}

/* ---- split-K reduce (bf16 partials) + bias -> d_out (fp32), 8 elems/thread ---- */
__global__ __launch_bounds__(256)
void reduce_kernel(const u16* __restrict__ p0, const u16* __restrict__ p1,
                   const float* __restrict__ b_o, float* __restrict__ out) {
  const int i = blockIdx.x * 256 + threadIdx.x;
  if (i >= MROWS * DIM_ / 8) return;
  const int col8 = i % (DIM_ / 8);
  const uint4 a = ((const uint4*)p0)[i];
  const uint4 b = ((const uint4*)p1)[i];
  const float4 c0 = ((const float4*)b_o)[col8 * 2];
  const float4 c1 = ((const float4*)b_o)[col8 * 2 + 1];
  float4 o0, o1;
  o0.x = bf2f((u16)(a.x & 0xffff)) + bf2f((u16)(b.x & 0xffff)) + c0.x;
  o0.y = bf2f((u16)(a.x >> 16))    + bf2f((u16)(b.x >> 16))    + c0.y;
  o0.z = bf2f((u16)(a.y & 0xffff)) + bf2f((u16)(b.y & 0xffff)) + c0.z;
  o0.w = bf2f((u16)(a.y >> 16))    + bf2f((u16)(b.y >> 16))    + c0.w;
  o1.x = bf2f((u16)(a.z & 0xffff)) + bf2f((u16)(b.z & 0xffff)) + c1.x;
  o1.y = bf2f((u16)(a.z >> 16))    + bf2f((u16)(b.z >> 16))    + c1.y;
  o1.z = bf2f((u16)(a.w & 0xffff)) + bf2f((u16)(b.w & 0xffff)) + c1.z;
  o1.w = bf2f((u16)(a.w >> 16))    + bf2f((u16)(b.w >> 16))    + c1.w;
  ((float4*)out)[i * 2]     = o0;
  ((float4*)out)[i * 2 + 1] = o1;
}

extern "C" void kernel_launch(void* const* d_in, const int* in_sizes, int n_in,
                              void* d_out, int out_size, void* d_ws, size_t ws_size,
                              hipStream_t stream) {
  const float* x       = (const float*)d_in[0];
  const float* w_q     = (const float*)d_in[1];
  const float* b_q     = (const float*)d_in[2];
  const float* w_k     = (const float*)d_in[3];
  const float* b_k     = (const float*)d_in[4];
  const float* w_v     = (const float*)d_in[5];
  const float* b_v     = (const float*)d_in[6];
  const float* w_o     = (const float*)d_in[7];
  const float* b_o     = (const float*)d_in[8];
  const float* g_q     = (const float*)d_in[9];
  const float* g_k     = (const float*)d_in[10];
  const float* cache_k = (const float*)d_in[11];
  const float* cache_v = (const float*)d_in[12];
  const float* rope_tb = (const float*)d_in[13];
  const int*   rope_ix = (const int*)d_in[14];
  const int*   cf      = (const int*)d_in[15];

  char* ws = (char*)d_ws;
  u16*   xb      = (u16*)(ws + OFF_XB);
  u16*   wb      = (u16*)(ws + OFF_WB);
  u16*   wob     = (u16*)(ws + OFF_WOB);
  float* bqkv    = (float*)(ws + OFF_BQKV);
  u16*   Cq      = (u16*)(ws + OFF_CQKV);
  u16*   attn_in = (u16*)(ws + OFF_ATTN);
  float* sctab   = (float*)(ws + OFF_SC);
  float* rms     = (float*)(ws + OFF_RMS);
  u16*   p0      = (u16*)(ws + OFF_P0);
  u16*   p1      = (u16*)(ws + OFF_P1);

  /* 1. all prep in one launch */
  prep_kernel<<<PREP_BLKS, 256, 0, stream>>>(x, w_q, w_k, w_v, w_o, b_q, b_k, b_v,
                                             rope_tb, rope_ix, cf, xb, wb, wob, bqkv, sctab);

  /* 2. QKV projection (2304 x 4608 x 1536), bf16 out, 648 blocks */
  gemm_bt_kernel<<<dim3(NQKV / 128, MPAD / 128, 1), 256, 0, stream>>>(
      xb, wb, bqkv, Cq, nullptr, DIM_, NQKV, MPAD, 1, DIM_);

  /* 3. per-row rms scalars for q,k (z<ZS rows) */
  rms_kernel<<<1024, 256, 0, stream>>>(Cq, rms);

  /* 4. temporal attention (split-g, depth-2 pipeline, fused norm+rope) + vcond */
  attention_kernel<<<ATTN_BLKS + VCOND_BLKS, 256, 0, stream>>>(
      Cq, cache_k, cache_v, sctab, rms, g_q, g_k, cf, attn_in);

  /* 5. output projection (2304 x 1536 x 1536), split-K=2, bf16 partials */
  gemm_bt_kernel<<<dim3(DIM_ / 128, MPAD / 128, 2), 256, 0, stream>>>(
      attn_in, wob, nullptr, p0, p1, DIM_, DIM_, MROWS, 2, KSPLIT);

  /* 6. reduce bf16 partials + bias -> d_out */
  reduce_kernel<<<(MROWS * DIM_ / 8 + 255) / 256, 256, 0, stream>>>(p0, p1, b_o, (float*)d_out);
}

// Round 9
// 216.677 us; speedup vs baseline: 1.0351x; 1.0351x over previous
//
#include <hip/hip_runtime.h>
#include <hip/hip_bf16.h>
#include <stdint.h>

typedef unsigned short u16;
typedef __attribute__((ext_vector_type(8))) short bf16x8;
typedef __attribute__((ext_vector_type(4))) float f32x4;

#define B_    8
#define L_    273
#define DIM_  1536
#define NH_   12
#define DH_   128
#define ZS_   256
#define FH_   32
#define MROWS (B_ * L_)   /* 2184 */
#define MPAD  2304        /* 18 * 128 */
#define NQKV  4608
#define WN_   (DIM_ * DIM_)      /* 2,359,296 */
#define WN8_  (WN_ / 8)          /* 294,912   */
#define X8_   (MROWS * DIM_ / 8) /* 419,328   */
#define XT8_  (MPAD * DIM_ / 8)  /* 442,368   */

/* prep_kernel region boundaries (threads); sctab has 33 frames (32 cached + cf) */
#define N0_ 442368
#define N1_ 737280
#define N2_ 1032192
#define N3_ 1327104
#define N4_ 1622016
#define N5_ 1626624
#define N6_ 2167296
#define PREP_BLKS 8466

/* attention geometry */
#define ATTN_ITEMS (B_ * ZS_ * 6)     /* 12288 */
#define ATTN_BLKS  (ATTN_ITEMS / 2)   /* 6144  */
#define VCOND_TOT  (B_ * (L_ - ZS_) * DIM_ / 8)  /* 26112 */
#define VCOND_BLKS ((VCOND_TOT + 255) / 256)     /* 102   */

#define KSPLIT 768

/* workspace offsets (bytes), all 16B-aligned */
#define OFF_XB    0ULL                      /* 2304*1536*2  = 7,077,888  */
#define OFF_WB    7077888ULL                /* 4608*1536*2  = 14,155,776 */
#define OFF_WOB   21233664ULL               /* 1536*1536*2  = 4,718,592  */
#define OFF_BQKV  25952256ULL               /* 4608*4       = 18,432     */
#define OFF_CQKV  25970688ULL               /* 2304*4608*2  = 21,233,664 (bf16) */
#define OFF_ATTN  47204352ULL               /* 2304*1536*2  = 7,077,888  */
#define OFF_SC    54282240ULL               /* 33*256*128*4 = 4,325,376  */
#define OFF_RMS   58607616ULL               /* 2*2048*4     = 16,384     */
/* split-K bf16 partials overlay dead regions:
 * p0 = [0, 7,077,888)           over xb        (dead after QKV GEMM)
 * p1 = [25,970,688, 33,048,576) over Cq        (dead after attention) */
#define OFF_P0    0ULL
#define OFF_P1    25970688ULL

__device__ __forceinline__ u16 f2bf(float f) {
  __hip_bfloat16 h = __float2bfloat16(f);
  return *reinterpret_cast<u16*>(&h);
}
__device__ __forceinline__ float bf2f(u16 v) {
  uint32_t u = ((uint32_t)v) << 16;
  return __uint_as_float(u);
}

__device__ __forceinline__ void gload_lds16(const u16* g, u16* l) {
  __builtin_amdgcn_global_load_lds(
      (const __attribute__((address_space(1))) void*)g,
      (__attribute__((address_space(3))) void*)l,
      16, 0, 0);
}

__device__ __forceinline__ void cast8(const float* __restrict__ s, u16* __restrict__ d,
                                      int i, int nvalid) {
  uint4 o;
  if (i < nvalid) {
    const float4 a = ((const float4*)s)[i * 2];
    const float4 b = ((const float4*)s)[i * 2 + 1];
    o.x = (uint32_t)f2bf(a.x) | ((uint32_t)f2bf(a.y) << 16);
    o.y = (uint32_t)f2bf(a.z) | ((uint32_t)f2bf(a.w) << 16);
    o.z = (uint32_t)f2bf(b.x) | ((uint32_t)f2bf(b.y) << 16);
    o.w = (uint32_t)f2bf(b.z) | ((uint32_t)f2bf(b.w) << 16);
  } else {
    o = make_uint4(0, 0, 0, 0);
  }
  ((uint4*)d)[i] = o;
}

/* ---- all input prep in ONE launch: casts, bias pack, rope sincos table.
 *      sctab frame 32 = current frame cf (for q-rope). ---- */
__global__ __launch_bounds__(256)
void prep_kernel(const float* __restrict__ x, const float* __restrict__ w_q,
                 const float* __restrict__ w_k, const float* __restrict__ w_v,
                 const float* __restrict__ w_o, const float* __restrict__ bq,
                 const float* __restrict__ bk, const float* __restrict__ bv,
                 const float* __restrict__ rope_tb, const int* __restrict__ rope_ix,
                 const int* __restrict__ cf_ptr,
                 u16* __restrict__ xb, u16* __restrict__ wb, u16* __restrict__ wob,
                 float* __restrict__ bqkv, float* __restrict__ sctab) {
  const int t = blockIdx.x * 256 + threadIdx.x;
  if (t < N0_)      cast8(x,   xb,           t,       X8_);
  else if (t < N1_) cast8(w_q, wb,           t - N0_, WN8_);
  else if (t < N2_) cast8(w_k, wb + WN_,     t - N1_, WN8_);
  else if (t < N3_) cast8(w_v, wb + 2 * WN_, t - N2_, WN8_);
  else if (t < N4_) cast8(w_o, wob,          t - N3_, WN8_);
  else if (t < N5_) {
    int i = t - N4_;
    float v;
    if (i < DIM_)          v = bq[i];
    else if (i < 2 * DIM_) v = bk[i - DIM_];
    else                   v = bv[i - 2 * DIM_];
    bqkv[i] = v;
  } else if (t < N6_) {
    int u = t - N5_;
    int j = u & 63;
    int idx = u >> 6;              /* f*ZS + z, f in [0,33) */
    int f = idx >> 8, z = idx & 255;
    int fi = (f == 32) ? *cf_ptr : rope_ix[f];
    float fr = rope_tb[((size_t)fi * L_ + z) * 64 + j];
    float sn, cn;
    __sincosf(fr, &sn, &cn);
    *(float2*)&sctab[((size_t)idx << 7) + 2 * j] = make_float2(sn, cn);
  }
}

/* ---- bf16 GEMM, C[m,n] = sum_k A[m,k]*B[n,k] (+bias)  (NT layout) ----
 * 128x128 tile, BK=32, 4 waves (2x2), double-buffered LDS, stage-early
 * (T3-minimum: one barrier per K-step). XCD-chunked block swizzle
 * (requires gridDim.x*gridDim.y % 8 == 0).
 * mode 1: bf16 out + bias; 2: bf16 partial (split-K via blockIdx.z, no bias). */
__global__ __launch_bounds__(256)
void gemm_bt_kernel(const u16* __restrict__ A, const u16* __restrict__ Bm,
                    const float* __restrict__ bias, void* __restrict__ Cv,
                    void* __restrict__ Cv2,
                    int K, int ldc, int Mvalid, int mode, int ksplit) {
  /* XCD swizzle: chunk tile-space so each XCD gets contiguous tiles */
  const int nwg = gridDim.x * gridDim.y;
  const int lin = blockIdx.y * gridDim.x + blockIdx.x;
  const int nl = (lin & 7) * (nwg >> 3) + (lin >> 3);
  const int tn = nl % gridDim.x, tm = nl / gridDim.x;

  const int tid = threadIdx.x;
  const int lane = tid & 63;
  const int wid = tid >> 6;
  const int wm = wid >> 1, wn = wid & 1;

  __shared__ __align__(16) u16 As[2][128 * 32];
  __shared__ __align__(16) u16 Bs[2][128 * 32];

  f32x4 acc[4][4] = {};

  const int srow = tid >> 2;
  const int scol = (tid & 3) * 8;
  const u16* Abase = A + (size_t)(tm * 128 + srow) * K + scol;
  const u16* Bbase = Bm + (size_t)(tn * 128 + srow) * K + scol;
  const size_t rstep = (size_t)64 * K;
  const int lofs = srow * 32 + scol;

  const int ko = (lane >> 4) * 8;
  const int rA = wm * 64 + (lane & 15);
  const int rB = wn * 64 + (lane & 15);

  const int k0 = blockIdx.z * ksplit;
  const int k1 = k0 + ksplit;

  gload_lds16(Abase + k0,         &As[0][lofs]);
  gload_lds16(Abase + k0 + rstep, &As[0][64 * 32 + lofs]);
  gload_lds16(Bbase + k0,         &Bs[0][lofs]);
  gload_lds16(Bbase + k0 + rstep, &Bs[0][64 * 32 + lofs]);
  __syncthreads();

  int cur = 0;
  for (int kt = k0; kt < k1; kt += 32) {
    const int nx = cur ^ 1;
    if (kt + 32 < k1) {           /* issue next-tile loads BEFORE compute */
      gload_lds16(Abase + kt + 32,         &As[nx][lofs]);
      gload_lds16(Abase + kt + 32 + rstep, &As[nx][64 * 32 + lofs]);
      gload_lds16(Bbase + kt + 32,         &Bs[nx][lofs]);
      gload_lds16(Bbase + kt + 32 + rstep, &Bs[nx][64 * 32 + lofs]);
    }
    bf16x8 af[4], bfr[4];
#pragma unroll
    for (int f = 0; f < 4; ++f) {
      af[f]  = *(const bf16x8*)&As[cur][(rA + f * 16) * 32 + ko];
      bfr[f] = *(const bf16x8*)&Bs[cur][(rB + f * 16) * 32 + ko];
    }
#pragma unroll
    for (int fm = 0; fm < 4; ++fm)
#pragma unroll
      for (int fn = 0; fn < 4; ++fn)
        acc[fm][fn] = __builtin_amdgcn_mfma_f32_16x16x32_bf16(af[fm], bfr[fn], acc[fm][fn], 0, 0, 0);
    __syncthreads();
    cur = nx;
  }

  const int m0 = tm * 128 + wm * 64 + (lane >> 4) * 4;
  const int n0 = tn * 128 + wn * 64 + (lane & 15);
  u16* Cp = (u16*)((mode == 2 && blockIdx.z) ? Cv2 : Cv);
#pragma unroll
  for (int fm = 0; fm < 4; ++fm) {
#pragma unroll
    for (int fn = 0; fn < 4; ++fn) {
      const int n = n0 + fn * 16;
      const float bv = (mode == 2) ? 0.f : bias[n];
#pragma unroll
      for (int r = 0; r < 4; ++r) {
        const int m = m0 + fm * 16 + r;
        if (m < Mvalid) {
          const float val = acc[fm][fn][r] + bv;
          Cp[(size_t)m * ldc + n] = f2bf(val);
        }
      }
    }
  }
}

/* ---- per-row rsqrt(mean(sq)) for q,k sections; z<ZS rows only.
 *      rms[sec*2048 + b*ZS + z]. One wave per (row, sec). ---- */
__global__ __launch_bounds__(256)
void rms_kernel(const u16* __restrict__ Cq, float* __restrict__ rms) {
  const int w = blockIdx.x * 4 + (threadIdx.x >> 6);   /* 0..4095 */
  const int lane = threadIdx.x & 63;
  const int sec = w & 1;
  const int rid = w >> 1;                              /* 0..2047 */
  const int b = rid >> 8, z = rid & 255;
  const u16* p = Cq + (size_t)(b * L_ + z) * NQKV + sec * DIM_;
  float ss = 0.f;
#pragma unroll
  for (int j = 0; j < 3; ++j) {
    bf16x8 v = *(const bf16x8*)&p[lane * 8 + j * 512];
#pragma unroll
    for (int e = 0; e < 8; ++e) {
      float f = bf2f((u16)v[e]);
      ss += f * f;
    }
  }
#pragma unroll
  for (int o = 32; o; o >>= 1) ss += __shfl_xor(ss, o);
  if (lane == 0)
    rms[sec * 2048 + rid] = rsqrtf(ss * (1.f / DIM_) + 1e-6f);
}

/* ---- attention: 2 waves per (b,z,head-pair) split over g; LDS merge.
 *      RMSNorm + gains + rope applied inline on raw q / slot-k.
 *      1-deep register prefetch of next-g cache k/v AND sincos (latency hiding).
 *      vcond passthrough blocks appended at the end of the grid. ---- */
__global__ __launch_bounds__(256)
void attention_kernel(const u16* __restrict__ Cq, const float* __restrict__ cache_k,
                      const float* __restrict__ cache_v, const float* __restrict__ sctab,
                      const float* __restrict__ rms, const float* __restrict__ g_q,
                      const float* __restrict__ g_k,
                      const int* __restrict__ cf_ptr, u16* __restrict__ attn_in) {
  if (blockIdx.x >= ATTN_BLKS) {
    int i = (blockIdx.x - ATTN_BLKS) * 256 + threadIdx.x;
    if (i < VCOND_TOT) {
      int e = i * 8;
      int col = e % DIM_;
      int r = e / DIM_;
      int b = r / (L_ - ZS_);
      int lz = r % (L_ - ZS_);
      size_t mrow = (size_t)b * L_ + ZS_ + lz;
      *(uint4*)&attn_in[mrow * DIM_ + col] = *(const uint4*)&Cq[mrow * NQKV + 2 * DIM_ + col];
    }
    return;
  }

  __shared__ float sm[2][64][6];
  const int p = threadIdx.x >> 7;          /* item within block */
  const int wi = (threadIdx.x >> 6) & 1;   /* wave within item  */
  const int lane = threadIdx.x & 63;
  const int item = blockIdx.x * 2 + p;
  const int hp = item % 6;
  const int z = (item / 6) % ZS_;
  const int b = item / (6 * ZS_);
  const int h = lane >> 5, il = lane & 31;
  const int n = hp * 2 + h;
  const int d0 = il * 4;
  const int cf = *cf_ptr;
  const int slot = cf % FH_;
  const int valid = min(cf + 1, FH_);
  const int g0 = (valid + 1) >> 1;
  const int gs = wi ? g0 : 0;
  const int ge = wi ? valid : g0;

  const size_t crow = (size_t)(b * L_ + z) * NQKV + n * DH_ + d0;
  const float rq = rms[b * ZS_ + z];
  float q0, q1, q2, q3;
  {
    ushort4 qv = *(const ushort4*)&Cq[crow];
    const float4 gq = *(const float4*)&g_q[n * DH_ + d0];
    const float u0 = bf2f(qv.x) * rq * gq.x;
    const float u1 = bf2f(qv.y) * rq * gq.y;
    const float u2 = bf2f(qv.z) * rq * gq.z;
    const float u3 = bf2f(qv.w) * rq * gq.w;
    const float4 scq = *(const float4*)&sctab[((size_t)(32 * ZS_ + z) << 7) + d0];
    q0 = u0 * scq.y - u1 * scq.x;
    q1 = u0 * scq.x + u1 * scq.y;
    q2 = u2 * scq.w - u3 * scq.z;
    q3 = u2 * scq.z + u3 * scq.w;
  }
  const float rk = rms[2048 + b * ZS_ + z];
  const float4 gk = *(const float4*)&g_k[n * DH_ + d0];

  auto loadkv = [&](int g, float4& ko, float4& vo) {
    if (g == slot) {
      ushort4 kv = *(const ushort4*)&Cq[crow + DIM_];
      ushort4 vv = *(const ushort4*)&Cq[crow + 2 * DIM_];
      ko.x = bf2f(kv.x) * rk * gk.x;
      ko.y = bf2f(kv.y) * rk * gk.y;
      ko.z = bf2f(kv.z) * rk * gk.z;
      ko.w = bf2f(kv.w) * rk * gk.w;
      vo.x = bf2f(vv.x); vo.y = bf2f(vv.y); vo.z = bf2f(vv.z); vo.w = bf2f(vv.w);
    } else {
      const size_t coff = ((((size_t)b * FH_ + g) * L_ + z) * NH_ + n) * DH_ + d0;
      ko = *(const float4*)&cache_k[coff];
      vo = *(const float4*)&cache_v[coff];
    }
  };

  float mx = -1e30f, lsum = 0.f;
  float a0 = 0.f, a1 = 0.f, a2 = 0.f, a3 = 0.f;
  if (gs < ge) {
    float4 kk, vv, sc;
    loadkv(gs, kk, vv);
    sc = *(const float4*)&sctab[((size_t)(gs * ZS_ + z) << 7) + d0];
    for (int g = gs; g < ge; ++g) {
      float4 kn, vn, sn;
      if (g + 1 < ge) {                      /* prefetch next g: k, v, sincos */
        loadkv(g + 1, kn, vn);
        sn = *(const float4*)&sctab[((size_t)((g + 1) * ZS_ + z) << 7) + d0];
      }
      const float kr0 = kk.x * sc.y - kk.y * sc.x;
      const float kr1 = kk.x * sc.x + kk.y * sc.y;
      const float kr2 = kk.z * sc.w - kk.w * sc.z;
      const float kr3 = kk.z * sc.z + kk.w * sc.w;
      float part = q0 * kr0 + q1 * kr1 + q2 * kr2 + q3 * kr3;
#pragma unroll
      for (int o = 16; o; o >>= 1) part += __shfl_xor(part, o);
      const float score = part * 0.088388347648318447f; /* 1/sqrt(128) */
      const float nm = fmaxf(mx, score);
      const float scl = __expf(mx - nm);
      const float pw = __expf(score - nm);
      lsum = lsum * scl + pw;
      a0 = a0 * scl + pw * vv.x;
      a1 = a1 * scl + pw * vv.y;
      a2 = a2 * scl + pw * vv.z;
      a3 = a3 * scl + pw * vv.w;
      mx = nm;
      kk = kn; vv = vn; sc = sn;
    }
  }

  if (wi == 1) {
    sm[p][lane][0] = mx;  sm[p][lane][1] = lsum;
    sm[p][lane][2] = a0;  sm[p][lane][3] = a1;
    sm[p][lane][4] = a2;  sm[p][lane][5] = a3;
  }
  __syncthreads();
  if (wi == 0) {
    const float mB = sm[p][lane][0], lB = sm[p][lane][1];
    const float M = fmaxf(mx, mB);
    const float wA = __expf(mx - M), wB = __expf(mB - M);
    const float L = lsum * wA + lB * wB;
    const float inv = 1.f / L;
    const float o0 = (a0 * wA + sm[p][lane][2] * wB) * inv;
    const float o1 = (a1 * wA + sm[p][lane][3] * wB) * inv;
    const float o2 = (a2 * wA + sm[p][lane][4] * wB) * inv;
    const float o3 = (a3 * wA + sm[p][lane][5] * wB) * inv;
    uint2 o;
    o.x = (uint32_t)f2bf(o0) | ((uint32_t)f2bf(o1) << 16);
    o.y = (uint32_t)f2bf(o2) | ((uint32_t)f2bf(o3) << 16);
    *(uint2*)&attn_in[(size_t)(b * L_ + z) * DIM_ + n * DH_ + d0] = o;
  }
}

/* ---- split-K reduce (bf16 partials) + bias -> d_out (fp32), 8 elems/thread ---- */
__global__ __launch_bounds__(256)
void reduce_kernel(const u16* __restrict__ p0, const u16* __restrict__ p1,
                   const float* __restrict__ b_o, float* __restrict__ out) {
  const int i = blockIdx.x * 256 + threadIdx.x;
  if (i >= MROWS * DIM_ / 8) return;
  const int col8 = i % (DIM_ / 8);
  const uint4 a = ((const uint4*)p0)[i];
  const uint4 b = ((const uint4*)p1)[i];
  const float4 c0 = ((const float4*)b_o)[col8 * 2];
  const float4 c1 = ((const float4*)b_o)[col8 * 2 + 1];
  float4 o0, o1;
  o0.x = bf2f((u16)(a.x & 0xffff)) + bf2f((u16)(b.x & 0xffff)) + c0.x;
  o0.y = bf2f((u16)(a.x >> 16))    + bf2f((u16)(b.x >> 16))    + c0.y;
  o0.z = bf2f((u16)(a.y & 0xffff)) + bf2f((u16)(b.y & 0xffff)) + c0.z;
  o0.w = bf2f((u16)(a.y >> 16))    + bf2f((u16)(b.y >> 16))    + c0.w;
  o1.x = bf2f((u16)(a.z & 0xffff)) + bf2f((u16)(b.z & 0xffff)) + c1.x;
  o1.y = bf2f((u16)(a.z >> 16))    + bf2f((u16)(b.z >> 16))    + c1.y;
  o1.z = bf2f((u16)(a.w & 0xffff)) + bf2f((u16)(b.w & 0xffff)) + c1.z;
  o1.w = bf2f((u16)(a.w >> 16))    + bf2f((u16)(b.w >> 16))    + c1.w;
  ((float4*)out)[i * 2]     = o0;
  ((float4*)out)[i * 2 + 1] = o1;
}

extern "C" void kernel_launch(void* const* d_in, const int* in_sizes, int n_in,
                              void* d_out, int out_size, void* d_ws, size_t ws_size,
                              hipStream_t stream) {
  const float* x       = (const float*)d_in[0];
  const float* w_q     = (const float*)d_in[1];
  const float* b_q     = (const float*)d_in[2];
  const float* w_k     = (const float*)d_in[3];
  const float* b_k     = (const float*)d_in[4];
  const float* w_v     = (const float*)d_in[5];
  const float* b_v     = (const float*)d_in[6];
  const float* w_o     = (const float*)d_in[7];
  const float* b_o     = (const float*)d_in[8];
  const float* g_q     = (const float*)d_in[9];
  const float* g_k     = (const float*)d_in[10];
  const float* cache_k = (const float*)d_in[11];
  const float* cache_v = (const float*)d_in[12];
  const float* rope_tb = (const float*)d_in[13];
  const int*   rope_ix = (const int*)d_in[14];
  const int*   cf      = (const int*)d_in[15];

  char* ws = (char*)d_ws;
  u16*   xb      = (u16*)(ws + OFF_XB);
  u16*   wb      = (u16*)(ws + OFF_WB);
  u16*   wob     = (u16*)(ws + OFF_WOB);
  float* bqkv    = (float*)(ws + OFF_BQKV);
  u16*   Cq      = (u16*)(ws + OFF_CQKV);
  u16*   attn_in = (u16*)(ws + OFF_ATTN);
  float* sctab   = (float*)(ws + OFF_SC);
  float* rms     = (float*)(ws + OFF_RMS);
  u16*   p0      = (u16*)(ws + OFF_P0);
  u16*   p1      = (u16*)(ws + OFF_P1);

  /* 1. all prep in one launch */
  prep_kernel<<<PREP_BLKS, 256, 0, stream>>>(x, w_q, w_k, w_v, w_o, b_q, b_k, b_v,
                                             rope_tb, rope_ix, cf, xb, wb, wob, bqkv, sctab);

  /* 2. QKV projection (2304 x 4608 x 1536), bf16 out, 648 blocks; skip pad rows */
  gemm_bt_kernel<<<dim3(NQKV / 128, MPAD / 128, 1), 256, 0, stream>>>(
      xb, wb, bqkv, Cq, nullptr, DIM_, NQKV, MROWS, 1, DIM_);

  /* 3. per-row rms scalars for q,k (z<ZS rows) */
  rms_kernel<<<1024, 256, 0, stream>>>(Cq, rms);

  /* 4. temporal attention (split-g, 1-deep k/v/sc prefetch, fused norm+rope) + vcond */
  attention_kernel<<<ATTN_BLKS + VCOND_BLKS, 256, 0, stream>>>(
      Cq, cache_k, cache_v, sctab, rms, g_q, g_k, cf, attn_in);

  /* 5. output projection (2304 x 1536 x 1536), split-K=2, bf16 partials */
  gemm_bt_kernel<<<dim3(DIM_ / 128, MPAD / 128, 2), 256, 0, stream>>>(
      attn_in, wob, nullptr, p0, p1, DIM_, DIM_, MROWS, 2, KSPLIT);

  /* 6. reduce bf16 partials + bias -> d_out */
  reduce_kernel<<<(MROWS * DIM_ / 8 + 255) / 256, 256, 0, stream>>>(p0, p1, b_o, (float*)d_out);
}